// Round 3
// baseline (120.903 us; speedup 1.0000x reference)
//
#include <hip/hip_runtime.h>
#include <hip/hip_bf16.h>

typedef __attribute__((ext_vector_type(4))) float  float4v;
typedef __attribute__((ext_vector_type(4))) short  short4v;
typedef __attribute__((ext_vector_type(8))) short  short8v;
typedef __attribute__((ext_vector_type(4))) float  f32x4;

// f32 -> bf16 RTNE via HW cvt (compiler emits v_cvt_pk_bf16_f32)
__device__ __forceinline__ short f2bf(float f) {
  __hip_bfloat16 h = __float2bfloat16(f);
  return *reinterpret_cast<short*>(&h);
}

__device__ __forceinline__ short8v cvt8(float4v v0, float4v v1) {
  short8v s;
  s[0]=f2bf(v0[0]); s[1]=f2bf(v0[1]); s[2]=f2bf(v0[2]); s[3]=f2bf(v0[3]);
  s[4]=f2bf(v1[0]); s[5]=f2bf(v1[1]); s[6]=f2bf(v1[2]); s[7]=f2bf(v1[3]);
  return s;
}

// XOR swizzle for LDS bf16 tiles: short idx k ^= ((row&7)<<3)
__device__ __forceinline__ int swz(int row, int k, int ld) {
  return row * ld + (k ^ ((row & 7) << 3));
}

// -------------------------------------------------------------------------
// Kernel 0: wt[f][d] = bf16(W[d][f])  (one-time 128x128 transpose+convert)
// grid 8 blocks x 256 thr; strided scalar reads (L2), coalesced 16B writes.
// -------------------------------------------------------------------------
__global__ __launch_bounds__(256) void k0_wt(const float* __restrict__ W,
                                             short* __restrict__ wt) {
  const int task = blockIdx.x * 256 + threadIdx.x;   // 2048 tasks
  const int f = task & 127;
  const int dc = (task >> 7) * 8;
  short8v s;
#pragma unroll
  for (int j = 0; j < 8; ++j) s[j] = f2bf(W[(size_t)(dc + j) * 128 + f]);
  *(short8v*)(wt + (size_t)f * 128 + dc) = s;
}

// -------------------------------------------------------------------------
// Kernel 1: ht[b][f][m] = bf16( sum_d feat[b][m][d] * W[d][f] )   (H^T)
// grid (N/64, B), 256 thr. Wave = 16 rows x 128 f. A-frags direct from
// global (contiguous per lane); W^T staged once from wt into LDS.
// -------------------------------------------------------------------------
__global__ __launch_bounds__(256) void k1_feat_x_w(
    const float* __restrict__ feat, const short* __restrict__ wt,
    short* __restrict__ ht, int N) {
  __shared__ short Ws[128 * 128];  // [f][d] bf16, swizzled (32 KB)
  const int t = threadIdx.x;
  const int batch = blockIdx.y;
  const int m0 = blockIdx.x * 64;
  const float* fb = feat + (size_t)batch * N * 128;

#pragma unroll
  for (int it = 0; it < 8; ++it) {
    const int idx = it * 256 + t;
    const int f = idx >> 4;
    const int dc = (idx & 15) * 8;
    short8v v = *(const short8v*)(wt + (size_t)f * 128 + dc);
    *(short8v*)(&Ws[swz(f, dc, 128)]) = v;
  }
  __syncthreads();

  const int lane = t & 63, wid = t >> 6;
  const int lr = lane & 15, lk = (lane >> 4) * 8;
  const float* pa = fb + (size_t)(m0 + wid * 16 + lr) * 128 + lk;

  f32x4 acc[8];
#pragma unroll
  for (int j = 0; j < 8; ++j) acc[j] = (f32x4){0.f, 0.f, 0.f, 0.f};

#pragma unroll
  for (int kk = 0; kk < 4; ++kk) {
    float4v v0 = ((const float4v*)(pa + kk * 32))[0];
    float4v v1 = ((const float4v*)(pa + kk * 32))[1];
    short8v a = cvt8(v0, v1);
#pragma unroll
    for (int ni = 0; ni < 8; ++ni) {
      short8v b = *(const short8v*)(&Ws[swz(ni * 16 + lr, kk * 32 + lk, 128)]);
      acc[ni] = __builtin_amdgcn_mfma_f32_16x16x32_bf16(a, b, acc[ni], 0, 0, 0);
    }
  }

  // store ht[b][f][m]; D-frag: col(f)=lane&15, row(m)=(lane>>4)*4+r
  short* hb = ht + (size_t)batch * 128 * N;
  const int m = m0 + wid * 16 + (lane >> 4) * 4;
#pragma unroll
  for (int ni = 0; ni < 8; ++ni) {
    const int f = ni * 16 + lr;
    short4v s;
#pragma unroll
    for (int r = 0; r < 4; ++r) s[r] = f2bf(acc[ni][r]);
    *(short4v*)(hb + (size_t)f * N + m) = s;
  }
}

// -------------------------------------------------------------------------
// Kernel 2: out[b][m][f] = relu( sum_k A[b][m][k] * H[k][f] + bias[f] )
// grid (N/64, B) = 256 blocks (1/CU), 256 thr = 4 waves.
// NO LDS / NO barriers in the K-loop: each wave loads MFMA fragments
// directly to registers (A reg-double-buffered across K-steps), so loads
// stay in flight continuously — no vmcnt(0) drain. Wave = 32 rows x 128 f
// x half-K (split-K 2, combined via LDS once at the end).
// -------------------------------------------------------------------------
__global__ __launch_bounds__(256, 1) void k2_a_x_h(
    const float* __restrict__ A, const short* __restrict__ ht,
    const float* __restrict__ bias, float* __restrict__ out, int N) {
  __shared__ f32x4 Cred[2][16 * 64];   // [m-pair][(ms*8+ni)*64+lane], 32 KB
  const int t = threadIdx.x;

  // XCD-chunked swizzle (bijective: nwg % 8 == 0 here)
  const int nwg = gridDim.x * gridDim.y;
  int wg = blockIdx.x + gridDim.x * blockIdx.y;
  if ((nwg & 7) == 0) wg = (wg & 7) * (nwg >> 3) + (wg >> 3);
  const int mtiles = gridDim.x;
  const int batch = wg / mtiles;
  const int m0 = (wg - batch * mtiles) * 64;

  const float* Ab = A + (size_t)batch * N * N;
  const short* hb = ht + (size_t)batch * 128 * N;

  const int lane = t & 63, wid = t >> 6;
  const int mp = wid & 1;    // which 32-row half of the block tile
  const int kh = wid >> 1;   // which K half
  const int lr = lane & 15, lk = (lane >> 4) * 8;
  const int khalf = N >> 1;

  const float* pa0 = Ab + (size_t)(m0 + mp * 32 + lr) * N + kh * khalf + lk;
  const float* pa1 = pa0 + (size_t)16 * N;
  const short* pb  = hb + (size_t)lr * N + kh * khalf + lk;

  f32x4 acc[2][8];
#pragma unroll
  for (int i = 0; i < 2; ++i)
#pragma unroll
    for (int j = 0; j < 8; ++j) acc[i][j] = (f32x4){0.f, 0.f, 0.f, 0.f};

  const int NSTEP = khalf >> 6;   // K-steps of 64 per wave (32)

  float4v buf0[8], buf1[8];

  auto loadA = [&](float4v (&buf)[8], int k0) {
    const float* p0 = pa0 + k0;
    const float* p1 = pa1 + k0;
    buf[0] = ((const float4v*)p0)[0];        buf[1] = ((const float4v*)p0)[1];
    buf[2] = ((const float4v*)(p0 + 32))[0]; buf[3] = ((const float4v*)(p0 + 32))[1];
    buf[4] = ((const float4v*)p1)[0];        buf[5] = ((const float4v*)p1)[1];
    buf[6] = ((const float4v*)(p1 + 32))[0]; buf[7] = ((const float4v*)(p1 + 32))[1];
  };
  auto step = [&](float4v (&buf)[8], int k0) {
    short8v a[2][2];
    a[0][0] = cvt8(buf[0], buf[1]);
    a[0][1] = cvt8(buf[2], buf[3]);
    a[1][0] = cvt8(buf[4], buf[5]);
    a[1][1] = cvt8(buf[6], buf[7]);
#pragma unroll
    for (int kk = 0; kk < 2; ++kk) {
      short8v b[8];
#pragma unroll
      for (int ni = 0; ni < 8; ++ni)
        b[ni] = *(const short8v*)(pb + (size_t)ni * 16 * N + k0 + kk * 32);
#pragma unroll
      for (int ni = 0; ni < 8; ++ni) {
        acc[0][ni] = __builtin_amdgcn_mfma_f32_16x16x32_bf16(a[0][kk], b[ni], acc[0][ni], 0, 0, 0);
        acc[1][ni] = __builtin_amdgcn_mfma_f32_16x16x32_bf16(a[1][kk], b[ni], acc[1][ni], 0, 0, 0);
      }
    }
  };

  loadA(buf0, 0);
  for (int s = 0; s < NSTEP; s += 2) {
    if (s + 1 < NSTEP) loadA(buf1, (s + 1) * 64);  // in flight across step s
    step(buf0, s * 64);
    if (s + 2 < NSTEP) loadA(buf0, (s + 2) * 64);  // in flight across step s+1
    if (s + 1 < NSTEP) step(buf1, (s + 1) * 64);
  }

  // split-K combine (the only barrier in the kernel)
  if (kh == 1) {
#pragma unroll
    for (int ms = 0; ms < 2; ++ms)
#pragma unroll
      for (int ni = 0; ni < 8; ++ni)
        Cred[mp][(ms * 8 + ni) * 64 + lane] = acc[ms][ni];
  }
  __syncthreads();
  if (kh == 0) {
    float* ob = out + (size_t)batch * N * 128;
#pragma unroll
    for (int ms = 0; ms < 2; ++ms) {
      const int mbase = m0 + mp * 32 + ms * 16 + (lane >> 4) * 4;
#pragma unroll
      for (int ni = 0; ni < 8; ++ni) {
        const f32x4 o = Cred[mp][(ms * 8 + ni) * 64 + lane];
        const int f = ni * 16 + lr;
        const float bv = bias[f];
#pragma unroll
        for (int r = 0; r < 4; ++r)
          ob[(size_t)(mbase + r) * 128 + f] = fmaxf(acc[ms][ni][r] + o[r] + bv, 0.f);
      }
    }
  }
}

extern "C" void kernel_launch(void* const* d_in, const int* in_sizes, int n_in,
                              void* d_out, int out_size, void* d_ws, size_t ws_size,
                              hipStream_t stream) {
  const float* feat = (const float*)d_in[0];  // [B,N,128]
  const float* A    = (const float*)d_in[1];  // [B,N,N]
  const float* W    = (const float*)d_in[2];  // [128,128]
  const float* bias = (const float*)d_in[3];  // [128]
  float* out = (float*)d_out;                 // [B,N,128]

  const int featN = in_sizes[0];      // B*N*128
  const int aN    = in_sizes[1];      // B*N*N
  const int BN    = featN / 128;      // B*N
  const int N     = aN / BN;
  const int Bb    = BN / N;

  short* wt = (short*)d_ws;           // [128][128] bf16 (32 KB)
  short* ht = wt + 128 * 128;         // [B][128][N] bf16

  dim3 blk(256);
  hipLaunchKernelGGL(k0_wt, dim3(8), blk, 0, stream, W, wt);
  hipLaunchKernelGGL(k1_feat_x_w, dim3(N / 64, Bb), blk, 0, stream, feat, wt, ht, N);
  hipLaunchKernelGGL(k2_a_x_h, dim3(N / 64, Bb), blk, 0, stream, A, ht, bias, out, N);
}

// Round 4
// 93.030 us; speedup vs baseline: 1.2996x; 1.2996x over previous
//
#include <hip/hip_runtime.h>
#include <hip/hip_bf16.h>

typedef __attribute__((ext_vector_type(4))) float  float4v;
typedef __attribute__((ext_vector_type(4))) short  short4v;
typedef __attribute__((ext_vector_type(8))) short  short8v;
typedef __attribute__((ext_vector_type(4))) float  f32x4;

// f32 -> bf16 RTNE via HW cvt (compiler emits v_cvt_pk_bf16_f32)
__device__ __forceinline__ short f2bf(float f) {
  __hip_bfloat16 h = __float2bfloat16(f);
  return *reinterpret_cast<short*>(&h);
}

__device__ __forceinline__ short8v cvt8(float4v v0, float4v v1) {
  short8v s;
  s[0]=f2bf(v0[0]); s[1]=f2bf(v0[1]); s[2]=f2bf(v0[2]); s[3]=f2bf(v0[3]);
  s[4]=f2bf(v1[0]); s[5]=f2bf(v1[1]); s[6]=f2bf(v1[2]); s[7]=f2bf(v1[3]);
  return s;
}

// XOR swizzle for LDS bf16 tiles: short idx k ^= ((row&7)<<3)
__device__ __forceinline__ int swz(int row, int k, int ld) {
  return row * ld + (k ^ ((row & 7) << 3));
}

// async global->LDS, 16B per lane; LDS dest = wave-uniform base + lane*16
__device__ __forceinline__ void gll16(const void* g, void* l) {
  __builtin_amdgcn_global_load_lds(
      (const __attribute__((address_space(1))) unsigned int*)g,
      (__attribute__((address_space(3))) unsigned int*)l, 16, 0, 0);
}

// -------------------------------------------------------------------------
// Kernel 0: wt[f][d] = bf16(W[d][f])  (one-time 128x128 transpose+convert)
// -------------------------------------------------------------------------
__global__ __launch_bounds__(256) void k0_wt(const float* __restrict__ W,
                                             short* __restrict__ wt) {
  const int task = blockIdx.x * 256 + threadIdx.x;   // 2048 tasks
  const int f = task & 127;
  const int dc = (task >> 7) * 8;
  short8v s;
#pragma unroll
  for (int j = 0; j < 8; ++j) s[j] = f2bf(W[(size_t)(dc + j) * 128 + f]);
  *(short8v*)(wt + (size_t)f * 128 + dc) = s;
}

// -------------------------------------------------------------------------
// Kernel 1: ht[b][f][m] = bf16( sum_d feat[b][m][d] * W[d][f] )   (H^T)
// grid (N/64, B), 256 thr. No LDS, no barrier: 4 independent waves; A-frags
// direct from feat (contiguous/lane); B-frags direct from wt (32 KB = L1).
// -------------------------------------------------------------------------
__global__ __launch_bounds__(256) void k1_feat_x_w(
    const float* __restrict__ feat, const short* __restrict__ wt,
    short* __restrict__ ht, int N) {
  const int t = threadIdx.x;
  const int batch = blockIdx.y;
  const int m0 = blockIdx.x * 64;
  const int lane = t & 63, wid = t >> 6;
  const int lr = lane & 15, lk = (lane >> 4) * 8;
  const float* pa = feat + (size_t)batch * N * 128
                  + (size_t)(m0 + wid * 16 + lr) * 128 + lk;

  f32x4 acc[8];
#pragma unroll
  for (int j = 0; j < 8; ++j) acc[j] = (f32x4){0.f, 0.f, 0.f, 0.f};

#pragma unroll
  for (int kk = 0; kk < 4; ++kk) {
    float4v v0 = ((const float4v*)(pa + kk * 32))[0];
    float4v v1 = ((const float4v*)(pa + kk * 32))[1];
    short8v a = cvt8(v0, v1);
#pragma unroll
    for (int ni = 0; ni < 8; ++ni) {
      short8v b = *(const short8v*)(wt + (size_t)(ni * 16 + lr) * 128 + kk * 32 + lk);
      acc[ni] = __builtin_amdgcn_mfma_f32_16x16x32_bf16(a, b, acc[ni], 0, 0, 0);
    }
  }

  // store ht[b][f][m]; D-frag: col(f)=lane&15, row(m)=(lane>>4)*4+r
  short* hb = ht + (size_t)batch * 128 * N;
  const int m = m0 + wid * 16 + (lane >> 4) * 4;
#pragma unroll
  for (int ni = 0; ni < 8; ++ni) {
    const int f = ni * 16 + lr;
    short4v s;
#pragma unroll
    for (int r = 0; r < 4; ++r) s[r] = f2bf(acc[ni][r]);
    *(short4v*)(hb + (size_t)f * N + m) = s;
  }
}

// -------------------------------------------------------------------------
// Kernel 2: out[b][m][f] = relu( sum_k A[b][m][k] * H[k][f] + bias[f] )
// grid (N/16, B) = 1024 blocks = 4/CU (16 waves/CU), 256 thr = 4 waves.
// 16x128 tile, BK=64. Double-buffered LDS; A reg-staged (f32->bf16);
// H via global_load_lds with pre-swizzled source. Prefetch-then-compute,
// one barrier per K-step; cross-block overlap hides the vmcnt drain.
// -------------------------------------------------------------------------
__global__ __launch_bounds__(256, 4) void k2_a_x_h(
    const float* __restrict__ A, const short* __restrict__ ht,
    const float* __restrict__ bias, float* __restrict__ out, int N) {
  __shared__ __align__(16) short As[2][16 * 64];    // 2 x 2 KB
  __shared__ __align__(16) short Hs[2][128 * 64];   // 2 x 16 KB
  const int t = threadIdx.x;

  // XCD-chunked swizzle (nwg = 1024, multiple of 8 -> bijective)
  const int nwg = gridDim.x * gridDim.y;
  int wg = blockIdx.x + gridDim.x * blockIdx.y;
  wg = (wg & 7) * (nwg >> 3) + (wg >> 3);
  const int mtiles = gridDim.x;
  const int batch = wg / mtiles;
  const int m0 = (wg - batch * mtiles) * 16;

  const float* Ab = A + (size_t)batch * N * N;
  const short* hb = ht + (size_t)batch * 128 * N;

  const int lane = t & 63, wid = t >> 6;
  const int lr = lane & 15, lk = (lane >> 4) * 8;

  // A staging map: thread covers 4 consecutive f32 (one float4)
  const int arow = t >> 4;        // 0..15
  const int akc = (t & 15) * 4;

  // H staging map (per wave, 4 gll16 calls of 16B/lane):
  const int hf = lane >> 3;          // 0..7 (row within 8-row group)
  const int hks = (lane & 7) * 8;    // k slot (shorts)

  float4v va;
  auto loadA = [&](int k0) {
    va = *(const float4v*)(Ab + (size_t)(m0 + arow) * N + k0 + akc);
  };
  auto writeA = [&](int buf) {
    short4v s;
#pragma unroll
    for (int i = 0; i < 4; ++i) s[i] = f2bf(va[i]);
    *(short4v*)(&As[buf][swz(arow, akc, 64)]) = s;
  };
  auto stageH = [&](int k0, int buf) {
#pragma unroll
    for (int i = 0; i < 4; ++i) {
      const int fb8 = (wid * 4 + i) * 8;         // wave-uniform f base
      const int f = fb8 + hf;
      // pre-swizzled global source so the LINEAR lds write lands swizzled
      const short* g = hb + (size_t)f * N + k0 + (hks ^ (hf << 3));
      gll16(g, &Hs[buf][fb8 * 64]);
    }
  };

  f32x4 acc[2];
  acc[0] = (f32x4){0.f, 0.f, 0.f, 0.f};
  acc[1] = (f32x4){0.f, 0.f, 0.f, 0.f};

  // prologue: stage tile 0 into buf 0
  loadA(0);
  stageH(0, 0);
  writeA(0);            // compiler inserts vmcnt wait for va only
  __syncthreads();      // drains gll writes too

  const int NT = N / 64;
  for (int tt = 0; tt < NT; ++tt) {
    const int cur = tt & 1;
    const bool pf = (tt + 1 < NT);
    if (pf) {
      loadA((tt + 1) * 64);           // HBM load in flight over MFMA phase
      stageH((tt + 1) * 64, cur ^ 1); // L2 loads direct to LDS
    }
#pragma unroll
    for (int kk = 0; kk < 2; ++kk) {
      const int k = kk * 32 + lk;
      short8v a = *(const short8v*)(&As[cur][swz(lr, k, 64)]);
#pragma unroll
      for (int ni = 0; ni < 2; ++ni) {
        short8v b = *(const short8v*)(&Hs[cur][swz(wid * 32 + ni * 16 + lr, k, 64)]);
        acc[ni] = __builtin_amdgcn_mfma_f32_16x16x32_bf16(a, b, acc[ni], 0, 0, 0);
      }
    }
    if (pf) writeA(cur ^ 1);
    __syncthreads();    // next tile fully staged
  }

  // epilogue: bias + relu; D-frag: col(f)=lane&15, row(m)=(lane>>4)*4+r
  float* ob = out + (size_t)batch * N * 128;
#pragma unroll
  for (int ni = 0; ni < 2; ++ni) {
    const int f = wid * 32 + ni * 16 + lr;
    const float bv = bias[f];
    const int mbase = m0 + (lane >> 4) * 4;
#pragma unroll
    for (int r = 0; r < 4; ++r)
      ob[(size_t)(mbase + r) * 128 + f] = fmaxf(acc[ni][r] + bv, 0.f);
  }
}

extern "C" void kernel_launch(void* const* d_in, const int* in_sizes, int n_in,
                              void* d_out, int out_size, void* d_ws, size_t ws_size,
                              hipStream_t stream) {
  const float* feat = (const float*)d_in[0];  // [B,N,128]
  const float* A    = (const float*)d_in[1];  // [B,N,N]
  const float* W    = (const float*)d_in[2];  // [128,128]
  const float* bias = (const float*)d_in[3];  // [128]
  float* out = (float*)d_out;                 // [B,N,128]

  const int featN = in_sizes[0];      // B*N*128
  const int aN    = in_sizes[1];      // B*N*N
  const int BN    = featN / 128;      // B*N
  const int N     = aN / BN;
  const int Bb    = BN / N;

  short* wt = (short*)d_ws;           // [128][128] bf16 (32 KB)
  short* ht = wt + 128 * 128;         // [B][128][N] bf16

  dim3 blk(256);
  hipLaunchKernelGGL(k0_wt, dim3(8), blk, 0, stream, W, wt);
  hipLaunchKernelGGL(k1_feat_x_w, dim3(N / 64, Bb), blk, 0, stream, feat, wt, ht, N);
  hipLaunchKernelGGL(k2_a_x_h, dim3(N / 16, Bb), blk, 0, stream, A, ht, bias, out, N);
}